// Round 2
// baseline (58.626 us; speedup 1.0000x reference)
//
#include <hip/hip_runtime.h>
#include <math.h>

#define THREADS 256

// b[j] = -k * ||y_j||^2
__global__ void kde_prep(const float* __restrict__ train, float* __restrict__ b,
                         int N, float negk) {
  int j = blockIdx.x * blockDim.x + threadIdx.x;
  if (j < N) {
    const float4* t = reinterpret_cast<const float4*>(train) + (size_t)j * 2;
    float4 y0 = t[0];
    float4 y1 = t[1];
    float s = y0.x * y0.x + y0.y * y0.y + y0.z * y0.z + y0.w * y0.w +
              y1.x * y1.x + y1.y * y1.y + y1.z * y1.z + y1.w * y1.w;
    b[j] = negk * s;
  }
}

// Each block: one 256-test tile x one train chunk. Per-thread partial sum
// of exp2(a_m + b_j + dot(2k*x_m, y_j)) over the chunk.
// 4-wide manual unroll with 4 independent exp/acc chains for ILP.
__global__ __launch_bounds__(THREADS) void kde_main(
    const float* __restrict__ test, const float* __restrict__ train,
    const float* __restrict__ b, float* __restrict__ partial,
    int M, int N, int nsplit, int chunk, float negk, float twok) {
  int tile = blockIdx.x / nsplit;
  int split = blockIdx.x - tile * nsplit;
  int m = tile * THREADS + threadIdx.x;
  if (m >= M) return;

  const float4* xp = reinterpret_cast<const float4*>(test) + (size_t)m * 2;
  float4 x0 = xp[0];
  float4 x1 = xp[1];
  float a = negk * (x0.x * x0.x + x0.y * x0.y + x0.z * x0.z + x0.w * x0.w +
                    x1.x * x1.x + x1.y * x1.y + x1.z * x1.z + x1.w * x1.w);
  // pre-scale x by 2k so per-iter arg = a + b[j] + dot(x', y_j)
  x0.x *= twok; x0.y *= twok; x0.z *= twok; x0.w *= twok;
  x1.x *= twok; x1.y *= twok; x1.z *= twok; x1.w *= twok;

  int j0 = split * chunk;
  int j1 = min(N, j0 + chunk);

#define DOT_ARG(jj)                                                      \
  ({                                                                     \
    const float* y_ = train + (size_t)(jj) * 8;                          \
    float d_ = fmaf(x0.x, y_[0], a + b[(jj)]);                           \
    d_ = fmaf(x0.y, y_[1], d_);                                          \
    d_ = fmaf(x0.z, y_[2], d_);                                          \
    d_ = fmaf(x0.w, y_[3], d_);                                          \
    d_ = fmaf(x1.x, y_[4], d_);                                          \
    d_ = fmaf(x1.y, y_[5], d_);                                          \
    d_ = fmaf(x1.z, y_[6], d_);                                          \
    fmaf(x1.w, y_[7], d_);                                               \
  })

  float acc0 = 0.0f, acc1 = 0.0f, acc2 = 0.0f, acc3 = 0.0f;
  int j = j0;
  for (; j + 4 <= j1; j += 4) {
    float g0 = DOT_ARG(j + 0);
    float g1 = DOT_ARG(j + 1);
    float g2 = DOT_ARG(j + 2);
    float g3 = DOT_ARG(j + 3);
    acc0 += __builtin_amdgcn_exp2f(g0);
    acc1 += __builtin_amdgcn_exp2f(g1);
    acc2 += __builtin_amdgcn_exp2f(g2);
    acc3 += __builtin_amdgcn_exp2f(g3);
  }
  for (; j < j1; ++j) acc0 += __builtin_amdgcn_exp2f(DOT_ARG(j));
#undef DOT_ARG

  partial[(size_t)split * M + m] = (acc0 + acc1) + (acc2 + acc3);
}

__global__ void kde_reduce(const float* __restrict__ partial,
                           float* __restrict__ out, int M, int nsplit,
                           float scale) {
  int m = blockIdx.x * blockDim.x + threadIdx.x;
  if (m < M) {
    float s = 0.0f;
    for (int i = 0; i < nsplit; ++i) s += partial[(size_t)i * M + m];
    out[m] = scale * s;
  }
}

extern "C" void kernel_launch(void* const* d_in, const int* in_sizes, int n_in,
                              void* d_out, int out_size, void* d_ws,
                              size_t ws_size, hipStream_t stream) {
  const float* test = (const float*)d_in[0];
  const float* train = (const float*)d_in[1];
  float* out = (float*)d_out;
  int M = in_sizes[0] / 8;
  int N = in_sizes[1] / 8;

  const double var = 0.05 * 0.05;
  const double k = 1.4426950408889634 / (2.0 * var);  // log2(e) / (2 var)
  const float negk = (float)(-k);
  const float twok = (float)(2.0 * k);
  const float coef = (float)(1.0 / sqrt(2.0 * M_PI * var));
  const float scale = coef / (float)N;

  // ws layout: [ b : N floats ][ partial : nsplit*M floats ]
  int nsplit = 128;
  size_t avail = ws_size / sizeof(float);
  while (nsplit > 1 && (size_t)N + (size_t)nsplit * (size_t)M > avail)
    nsplit >>= 1;
  float* b = (float*)d_ws;
  float* partial = b + N;
  int chunk = (N + nsplit - 1) / nsplit;

  kde_prep<<<(N + 255) / 256, 256, 0, stream>>>(train, b, N, negk);
  int ntiles = (M + THREADS - 1) / THREADS;
  kde_main<<<ntiles * nsplit, THREADS, 0, stream>>>(test, train, b, partial, M,
                                                    N, nsplit, chunk, negk,
                                                    twok);
  kde_reduce<<<(M + 255) / 256, 256, 0, stream>>>(partial, out, M, nsplit,
                                                  scale);
}

// Round 3
// 24.378 us; speedup vs baseline: 2.4049x; 2.4049x over previous
//
#include <hip/hip_runtime.h>
#include <math.h>

#define THREADS 256
#define PTS 2
#define TILE (THREADS * PTS)  // 512 test points per block
#define CHUNK 64              // train rows staged per block iteration

__global__ __launch_bounds__(THREADS) void kde_main(
    const float* __restrict__ test, const float* __restrict__ train,
    float* __restrict__ partial, int M, int N, int nsplit, float negk,
    float twok) {
  __shared__ float4 ylds[CHUNK * 2];  // CHUNK rows x 8 floats
  __shared__ float blds[CHUNK];       // -k*||y||^2 per row

  int tile = blockIdx.x / nsplit;
  int split = blockIdx.x - tile * nsplit;

  int mA = tile * TILE + threadIdx.x;
  int mB = mA + THREADS;

  // Load + prescale the two test points (coalesced float4 loads).
  const float4* xp = reinterpret_cast<const float4*>(test);
  int ma = min(mA, M - 1), mb = min(mB, M - 1);
  float4 x0a = xp[(size_t)ma * 2], x1a = xp[(size_t)ma * 2 + 1];
  float4 x0b = xp[(size_t)mb * 2], x1b = xp[(size_t)mb * 2 + 1];
  float aA = negk * (x0a.x * x0a.x + x0a.y * x0a.y + x0a.z * x0a.z +
                     x0a.w * x0a.w + x1a.x * x1a.x + x1a.y * x1a.y +
                     x1a.z * x1a.z + x1a.w * x1a.w);
  float aB = negk * (x0b.x * x0b.x + x0b.y * x0b.y + x0b.z * x0b.z +
                     x0b.w * x0b.w + x1b.x * x1b.x + x1b.y * x1b.y +
                     x1b.z * x1b.z + x1b.w * x1b.w);
  // prescale by 2k so arg = a + b_j + dot(x', y_j)
  x0a.x *= twok; x0a.y *= twok; x0a.z *= twok; x0a.w *= twok;
  x1a.x *= twok; x1a.y *= twok; x1a.z *= twok; x1a.w *= twok;
  x0b.x *= twok; x0b.y *= twok; x0b.z *= twok; x0b.w *= twok;
  x1b.x *= twok; x1b.y *= twok; x1b.z *= twok; x1b.w *= twok;

  float accA = 0.0f, accB = 0.0f;

  int nchunks = (N + CHUNK - 1) / CHUNK;
  for (int c = split; c < nchunks; c += nsplit) {
    int j0 = c * CHUNK;
    int nrow = min(CHUNK, N - j0);

    __syncthreads();  // protect LDS reuse across chunk iterations
    if (threadIdx.x < 2 * CHUNK) {
      int idx = 2 * j0 + threadIdx.x;
      if (idx < 2 * N)
        ylds[threadIdx.x] = reinterpret_cast<const float4*>(train)[idx];
    }
    __syncthreads();
    if (threadIdx.x < CHUNK && threadIdx.x < nrow) {
      float4 y0 = ylds[threadIdx.x * 2], y1 = ylds[threadIdx.x * 2 + 1];
      blds[threadIdx.x] =
          negk * (y0.x * y0.x + y0.y * y0.y + y0.z * y0.z + y0.w * y0.w +
                  y1.x * y1.x + y1.y * y1.y + y1.z * y1.z + y1.w * y1.w);
    }
    __syncthreads();

#define BODY(r)                                           \
  {                                                       \
    float4 y0 = ylds[2 * (r)], y1 = ylds[2 * (r) + 1];    \
    float bj = blds[(r)];                                 \
    float gA = fmaf(x0a.x, y0.x, aA + bj);                \
    gA = fmaf(x0a.y, y0.y, gA);                           \
    gA = fmaf(x0a.z, y0.z, gA);                           \
    gA = fmaf(x0a.w, y0.w, gA);                           \
    gA = fmaf(x1a.x, y1.x, gA);                           \
    gA = fmaf(x1a.y, y1.y, gA);                           \
    gA = fmaf(x1a.z, y1.z, gA);                           \
    gA = fmaf(x1a.w, y1.w, gA);                           \
    float gB = fmaf(x0b.x, y0.x, aB + bj);                \
    gB = fmaf(x0b.y, y0.y, gB);                           \
    gB = fmaf(x0b.z, y0.z, gB);                           \
    gB = fmaf(x0b.w, y0.w, gB);                           \
    gB = fmaf(x1b.x, y1.x, gB);                           \
    gB = fmaf(x1b.y, y1.y, gB);                           \
    gB = fmaf(x1b.z, y1.z, gB);                           \
    gB = fmaf(x1b.w, y1.w, gB);                           \
    accA += __builtin_amdgcn_exp2f(gA);                   \
    accB += __builtin_amdgcn_exp2f(gB);                   \
  }

    if (nrow == CHUNK) {
#pragma unroll 4
      for (int r = 0; r < CHUNK; ++r) BODY(r);
    } else {
      for (int r = 0; r < nrow; ++r) BODY(r);
    }
#undef BODY
  }

  if (mA < M) partial[(size_t)split * M + mA] = accA;
  if (mB < M) partial[(size_t)split * M + mB] = accB;
}

__global__ void kde_reduce(const float* __restrict__ partial,
                           float* __restrict__ out, int M, int nsplit,
                           float scale) {
  int m = blockIdx.x * blockDim.x + threadIdx.x;
  if (m >= M) return;
  float s0 = 0, s1 = 0, s2 = 0, s3 = 0, s4 = 0, s5 = 0, s6 = 0, s7 = 0;
  int i = 0;
  for (; i + 8 <= nsplit; i += 8) {
    s0 += partial[(size_t)(i + 0) * M + m];
    s1 += partial[(size_t)(i + 1) * M + m];
    s2 += partial[(size_t)(i + 2) * M + m];
    s3 += partial[(size_t)(i + 3) * M + m];
    s4 += partial[(size_t)(i + 4) * M + m];
    s5 += partial[(size_t)(i + 5) * M + m];
    s6 += partial[(size_t)(i + 6) * M + m];
    s7 += partial[(size_t)(i + 7) * M + m];
  }
  for (; i < nsplit; ++i) s0 += partial[(size_t)i * M + m];
  out[m] = scale * (((s0 + s1) + (s2 + s3)) + ((s4 + s5) + (s6 + s7)));
}

extern "C" void kernel_launch(void* const* d_in, const int* in_sizes, int n_in,
                              void* d_out, int out_size, void* d_ws,
                              size_t ws_size, hipStream_t stream) {
  const float* test = (const float*)d_in[0];
  const float* train = (const float*)d_in[1];
  float* out = (float*)d_out;
  int M = in_sizes[0] / 8;
  int N = in_sizes[1] / 8;

  const double var = 0.05 * 0.05;
  const double k = 1.4426950408889634 / (2.0 * var);  // log2(e)/(2 var)
  const float negk = (float)(-k);
  const float twok = (float)(2.0 * k);
  const float coef = (float)(1.0 / sqrt(2.0 * M_PI * var));
  const float scale = coef / (float)N;

  // ws layout: [ partial : nsplit*M floats ]
  int nsplit = 128;
  size_t avail = ws_size / sizeof(float);
  while (nsplit > 1 && (size_t)nsplit * (size_t)M > avail) nsplit >>= 1;
  float* partial = (float*)d_ws;

  int ntiles = (M + TILE - 1) / TILE;
  kde_main<<<ntiles * nsplit, THREADS, 0, stream>>>(test, train, partial, M, N,
                                                    nsplit, negk, twok);
  kde_reduce<<<(M + 255) / 256, 256, 0, stream>>>(partial, out, M, nsplit,
                                                  scale);
}